// Round 1
// baseline (392.348 us; speedup 1.0000x reference)
//
#include <hip/hip_runtime.h>
#include <hip/hip_bf16.h>

// Problem constants (match reference)
#define N_ATOMS_C   100000
#define CUTOFF_C    12.0f
#define CUTOFF_SR_C 2.0f
#define CUTOFF_SQ_C 144.0f
#define KEHALF_C    7.199822675975274f

// Each thread processes 4 consecutive edges (float4/int4 vector loads),
// computes the blended shielded/ordinary Coulomb + dipole energy, and
// atomicAdds into out[idx_i]. Random idx spreads atomics over 100K words,
// so per-address contention is low; the serialization cost is L2-side
// atomic throughput, not same-address conflicts.
__global__ __launch_bounds__(256) void pc_dipole_edges(
    const float* __restrict__ q,
    const float* __restrict__ dip,
    const float* __restrict__ dist,
    const int*   __restrict__ idx_i,
    const int*   __restrict__ idx_j,
    float*       __restrict__ out,
    int n_edges)
{
    const int n4 = n_edges >> 2;           // number of full float4 groups
    int t = blockIdx.x * blockDim.x + threadIdx.x;
    const int stride = gridDim.x * blockDim.x;

    const float4* dist4  = (const float4*)dist;
    const int4*   idxi4  = (const int4*)idx_i;
    const int4*   idxj4  = (const int4*)idx_j;

    for (int g = t; g < n4; g += stride) {
        float4 d4 = dist4[g];
        int4   i4 = idxi4[g];
        int4   j4 = idxj4[g];

        #pragma unroll
        for (int k = 0; k < 4; ++k) {
            float d = (k == 0) ? d4.x : (k == 1) ? d4.y : (k == 2) ? d4.z : d4.w;
            int   i = (k == 0) ? i4.x : (k == 1) ? i4.y : (k == 2) ? i4.z : i4.w;
            int   j = (k == 0) ? j4.x : (k == 1) ? j4.y : (k == 2) ? j4.z : j4.w;

            if (d > CUTOFF_C) continue;    // E == 0, skip gather + atomic

            float qi = q[i],   qj = q[j];
            float di = dip[i], dj = dip[j];

            float inv_d   = __frcp_rn(d);
            float dsh     = __fsqrt_rn(fmaf(d, d, 1.0f));
            float inv_dsh = __frcp_rn(dsh);

            // poly6 switch on [0, CUTOFF_SR): 1 - 10x^3 + 15x^4 - 6x^5
            float x  = d * (1.0f / CUTOFF_SR_C);
            float x3 = x * x * x;
            float sw = fmaf(x3, fmaf(x, fmaf(x, -6.0f, 15.0f), -10.0f), 1.0f);
            float sw_off = (d < CUTOFF_SR_C) ? sw : 0.0f;

            // shifted-force Coulomb
            float Eoq = inv_d   + fmaf(d,   (1.0f / CUTOFF_SQ_C), -(2.0f / CUTOFF_C));
            float Esq = inv_dsh + fmaf(dsh, (1.0f / CUTOFF_SQ_C), -(2.0f / CUTOFF_C));
            // blend: sw_off*Esh + (1-sw_off)*Eord = Eord + sw_off*(Esh - Eord)
            float Eq  = (KEHALF_C * qi * qj) * fmaf(sw_off, Esq - Eoq, Eoq);

            // dipole-dipole ~ 1/d^3
            float Eod = inv_d * inv_d * inv_d;
            float Esd = inv_dsh * inv_dsh * inv_dsh;
            float Ed  = (KEHALF_C * di * dj) * fmaf(sw_off, Esd - Eod, Eod);

            atomicAdd(&out[i], Eq + Ed);
        }
    }

    // tail (n_edges not divisible by 4) — handled by the first few threads
    int rem_start = n4 << 2;
    for (int e = rem_start + t; e < n_edges; e += stride) {
        float d = dist[e];
        if (d > CUTOFF_C) continue;
        int i = idx_i[e], j = idx_j[e];
        float qi = q[i], qj = q[j];
        float di = dip[i], dj = dip[j];
        float inv_d   = __frcp_rn(d);
        float dsh     = __fsqrt_rn(fmaf(d, d, 1.0f));
        float inv_dsh = __frcp_rn(dsh);
        float x  = d * (1.0f / CUTOFF_SR_C);
        float x3 = x * x * x;
        float sw = fmaf(x3, fmaf(x, fmaf(x, -6.0f, 15.0f), -10.0f), 1.0f);
        float sw_off = (d < CUTOFF_SR_C) ? sw : 0.0f;
        float Eoq = inv_d   + fmaf(d,   (1.0f / CUTOFF_SQ_C), -(2.0f / CUTOFF_C));
        float Esq = inv_dsh + fmaf(dsh, (1.0f / CUTOFF_SQ_C), -(2.0f / CUTOFF_C));
        float Eq  = (KEHALF_C * qi * qj) * fmaf(sw_off, Esq - Eoq, Eoq);
        float Eod = inv_d * inv_d * inv_d;
        float Esd = inv_dsh * inv_dsh * inv_dsh;
        float Ed  = (KEHALF_C * di * dj) * fmaf(sw_off, Esd - Eod, Eod);
        atomicAdd(&out[i], Eq + Ed);
    }
}

extern "C" void kernel_launch(void* const* d_in, const int* in_sizes, int n_in,
                              void* d_out, int out_size, void* d_ws, size_t ws_size,
                              hipStream_t stream) {
    const float* q     = (const float*)d_in[0];   // atomic_charges [N_ATOMS]
    const float* dip   = (const float*)d_in[1];   // atomic_dipoles [N_ATOMS]
    const float* dist  = (const float*)d_in[2];   // distances      [N_EDGES]
    const int*   idx_i = (const int*)d_in[3];     // [N_EDGES]
    const int*   idx_j = (const int*)d_in[4];     // [N_EDGES]
    float*       out   = (float*)d_out;           // [N_ATOMS]

    int n_edges = in_sizes[2];

    // Output is re-poisoned to 0xAA before every timed launch — must zero it.
    hipMemsetAsync(out, 0, (size_t)out_size * sizeof(float), stream);

    // 4 edges per thread; saturate 256 CUs with plenty of waves.
    int n4 = (n_edges + 3) >> 2;
    int block = 256;
    int grid = (n4 + block - 1) / block;
    if (grid > 65535 * 16) grid = 65535 * 16;  // safety clamp (never hit here)

    pc_dipole_edges<<<grid, block, 0, stream>>>(q, dip, dist, idx_i, idx_j,
                                                out, n_edges);
}

// Round 2
// 259.344 us; speedup vs baseline: 1.5129x; 1.5129x over previous
//
#include <hip/hip_runtime.h>
#include <hip/hip_bf16.h>

// Problem constants (match reference)
#define N_ATOMS_C   100000
#define CUTOFF_C    12.0f
#define CUTOFF_SR_C 2.0f
#define CUTOFF_SQ_C 144.0f
#define KEHALF_C    7.199822675975274f

// Privatization parameters:
// CHUNK*4 = 64000 B LDS accumulator -> 2 blocks/CU (160 KiB pool), and it
// stays under the 64 KiB static-__shared__ per-workgroup limit.
#define CHUNK   16000
#define NCHUNK  7          // ceil(100000 / 16000)
#define BLOCK1  512        // 8 waves/block * 2 blocks/CU = 16 waves/CU
#define MAX_S   73         // 73*7 = 511 blocks ~= 2 per CU, evenly loaded

__device__ __forceinline__ float edge_energy(float d, float qi, float qj,
                                             float di, float dj) {
    float inv_d   = __frcp_rn(d);
    float dsh     = __fsqrt_rn(fmaf(d, d, 1.0f));
    float inv_dsh = __frcp_rn(dsh);

    // poly6 switch on [0, CUTOFF_SR): 1 - 10x^3 + 15x^4 - 6x^5
    float x  = d * (1.0f / CUTOFF_SR_C);
    float x3 = x * x * x;
    float sw = fmaf(x3, fmaf(x, fmaf(x, -6.0f, 15.0f), -10.0f), 1.0f);
    float sw_off = (d < CUTOFF_SR_C) ? sw : 0.0f;

    // shifted-force Coulomb, blended shielded/ordinary
    float Eoq = inv_d   + fmaf(d,   (1.0f / CUTOFF_SQ_C), -(2.0f / CUTOFF_C));
    float Esq = inv_dsh + fmaf(dsh, (1.0f / CUTOFF_SQ_C), -(2.0f / CUTOFF_C));
    float Eq  = (KEHALF_C * qi * qj) * fmaf(sw_off, Esq - Eoq, Eoq);

    // dipole-dipole ~ 1/d^3
    float Eod = inv_d * inv_d * inv_d;
    float Esd = inv_dsh * inv_dsh * inv_dsh;
    float Ed  = (KEHALF_C * di * dj) * fmaf(sw_off, Esd - Eod, Eod);

    return Eq + Ed;
}

// Phase 1: block (s, c) scans edge-slice s, accumulates atoms of chunk c
// into a private LDS array, then flushes 16K partials with PLAIN coalesced
// stores (no global atomics anywhere).
__global__ __launch_bounds__(BLOCK1) void pc_dipole_phase1(
    const float* __restrict__ q,
    const float* __restrict__ dip,
    const float* __restrict__ dist,
    const int*   __restrict__ idx_i,
    const int*   __restrict__ idx_j,
    float*       __restrict__ partial,   // [S][NCHUNK*CHUNK]
    int n_edges, int S, int gps)
{
    __shared__ float acc[CHUNK];

    const int c    = blockIdx.x % NCHUNK;
    const int s    = blockIdx.x / NCHUNK;
    const int base = c * CHUNK;

    for (int i = threadIdx.x; i < CHUNK; i += BLOCK1) acc[i] = 0.0f;
    __syncthreads();

    const int n4 = n_edges >> 2;
    const int g0 = s * gps;
    const int g1 = min(g0 + gps, n4);

    const float4* dist4 = (const float4*)dist;
    const int4*   idxi4 = (const int4*)idx_i;

    for (int g = g0 + (int)threadIdx.x; g < g1; g += BLOCK1) {
        int4   i4 = idxi4[g];   // coalesced 16B; L3-hot after first chunk pass
        float4 d4 = dist4[g];
        int e = g << 2;
        #pragma unroll
        for (int k = 0; k < 4; ++k) {
            int   i = (k == 0) ? i4.x : (k == 1) ? i4.y : (k == 2) ? i4.z : i4.w;
            float d = (k == 0) ? d4.x : (k == 1) ? d4.y : (k == 2) ? d4.z : d4.w;
            unsigned local = (unsigned)(i - base);
            if (local < (unsigned)CHUNK && d <= CUTOFF_C) {
                int j = idx_j[e + k];             // gather, ~1/7 lanes active
                float E = edge_energy(d, q[i], q[j], dip[i], dip[j]);
                atomicAdd(&acc[local], E);        // ds_add_f32, random banks
            }
        }
    }

    // tail (n_edges % 4) handled by the last slice's blocks
    if (s == S - 1) {
        for (int e = (n4 << 2) + (int)threadIdx.x; e < n_edges; e += BLOCK1) {
            int i = idx_i[e];
            float d = dist[e];
            unsigned local = (unsigned)(i - base);
            if (local < (unsigned)CHUNK && d <= CUTOFF_C) {
                int j = idx_j[e];
                float E = edge_energy(d, q[i], q[j], dip[i], dip[j]);
                atomicAdd(&acc[local], E);
            }
        }
    }

    __syncthreads();
    float* dst = partial + (size_t)(s * NCHUNK + c) * CHUNK;
    for (int i = threadIdx.x; i < CHUNK; i += BLOCK1) dst[i] = acc[i];
}

// Phase 2: out[a] = sum_s partial[s][a]. Coalesced, no atomics; writes every
// output element so no memset of d_out is needed.
__global__ __launch_bounds__(256) void pc_dipole_phase2(
    const float* __restrict__ partial,
    float*       __restrict__ out,
    int n_atoms, int S)
{
    int a = blockIdx.x * 256 + threadIdx.x;
    if (a >= n_atoms) return;
    int c     = a / CHUNK;
    int local = a % CHUNK;
    const float* p = partial + (size_t)c * CHUNK + local;
    const size_t stride = (size_t)NCHUNK * CHUNK;

    float s0 = 0.f, s1 = 0.f, s2 = 0.f, s3 = 0.f;
    int s = 0;
    for (; s + 4 <= S; s += 4) {
        s0 += p[(size_t)(s + 0) * stride];
        s1 += p[(size_t)(s + 1) * stride];
        s2 += p[(size_t)(s + 2) * stride];
        s3 += p[(size_t)(s + 3) * stride];
    }
    for (; s < S; ++s) s0 += p[(size_t)s * stride];
    out[a] = (s0 + s1) + (s2 + s3);
}

// Fallback (ws too small): round-1 global-atomic kernel. Kept for safety.
__global__ __launch_bounds__(256) void pc_dipole_edges_atomic(
    const float* __restrict__ q,
    const float* __restrict__ dip,
    const float* __restrict__ dist,
    const int*   __restrict__ idx_i,
    const int*   __restrict__ idx_j,
    float*       __restrict__ out,
    int n_edges)
{
    int t = blockIdx.x * blockDim.x + threadIdx.x;
    const int stride = gridDim.x * blockDim.x;
    for (int e = t; e < n_edges; e += stride) {
        float d = dist[e];
        if (d > CUTOFF_C) continue;
        int i = idx_i[e], j = idx_j[e];
        float E = edge_energy(d, q[i], q[j], dip[i], dip[j]);
        atomicAdd(&out[i], E);
    }
}

extern "C" void kernel_launch(void* const* d_in, const int* in_sizes, int n_in,
                              void* d_out, int out_size, void* d_ws, size_t ws_size,
                              hipStream_t stream) {
    const float* q     = (const float*)d_in[0];   // atomic_charges [N_ATOMS]
    const float* dip   = (const float*)d_in[1];   // atomic_dipoles [N_ATOMS]
    const float* dist  = (const float*)d_in[2];   // distances      [N_EDGES]
    const int*   idx_i = (const int*)d_in[3];
    const int*   idx_j = (const int*)d_in[4];
    float*       out   = (float*)d_out;

    int n_edges = in_sizes[2];
    int n_atoms = out_size;

    const size_t per_slice = (size_t)NCHUNK * CHUNK * sizeof(float);
    int S = (int)(ws_size / per_slice);
    if (S > MAX_S) S = MAX_S;

    if (S >= 1 && n_atoms <= NCHUNK * CHUNK) {
        float* partial = (float*)d_ws;
        int n4  = n_edges >> 2;
        int gps = (n4 + S - 1) / S;
        pc_dipole_phase1<<<S * NCHUNK, BLOCK1, 0, stream>>>(
            q, dip, dist, idx_i, idx_j, partial, n_edges, S, gps);
        pc_dipole_phase2<<<(n_atoms + 255) / 256, 256, 0, stream>>>(
            partial, out, n_atoms, S);
    } else {
        // Safety fallback: global atomics (output must be zeroed first).
        hipMemsetAsync(out, 0, (size_t)n_atoms * sizeof(float), stream);
        int block = 256;
        int grid  = (n_edges + block - 1) / block;
        pc_dipole_edges_atomic<<<grid, block, 0, stream>>>(
            q, dip, dist, idx_i, idx_j, out, n_edges);
    }
}

// Round 3
// 238.385 us; speedup vs baseline: 1.6459x; 1.0879x over previous
//
#include <hip/hip_runtime.h>
#include <hip/hip_bf16.h>

// Problem constants (match reference)
#define CUTOFF_C    12.0f
#define CUTOFF_SR_C 2.0f
#define CUTOFF_SQ_C 144.0f
#define KEHALF_C    7.199822675975274f

#define CHUNK    16000     // 64000 B LDS accumulator (<= 64 KiB static limit)
#define NCHUNK   7         // ceil(100000 / 16000)
#define BLOCK_SC 512       // scatter block: 8 waves; 2 blocks/CU by LDS
#define S_FULL   72        // 72*7 = 504 blocks ~= 2/CU; 72 = 8 XCDs * 9

__device__ __forceinline__ float edge_energy(float d, float qi, float qj,
                                             float di, float dj) {
    float inv_d   = __frcp_rn(d);
    float dsh     = __fsqrt_rn(fmaf(d, d, 1.0f));
    float inv_dsh = __frcp_rn(dsh);

    // poly6 switch on [0, CUTOFF_SR): 1 - 10x^3 + 15x^4 - 6x^5
    float x  = d * (1.0f / CUTOFF_SR_C);
    float x3 = x * x * x;
    float sw = fmaf(x3, fmaf(x, fmaf(x, -6.0f, 15.0f), -10.0f), 1.0f);
    float sw_off = (d < CUTOFF_SR_C) ? sw : 0.0f;

    float Eoq = inv_d   + fmaf(d,   (1.0f / CUTOFF_SQ_C), -(2.0f / CUTOFF_C));
    float Esq = inv_dsh + fmaf(dsh, (1.0f / CUTOFF_SQ_C), -(2.0f / CUTOFF_C));
    float Eq  = (KEHALF_C * qi * qj) * fmaf(sw_off, Esq - Eoq, Eoq);

    float Eod = inv_d * inv_d * inv_d;
    float Esd = inv_dsh * inv_dsh * inv_dsh;
    float Ed  = (KEHALF_C * di * dj) * fmaf(sw_off, Esd - Eod, Eod);

    return Eq + Ed;
}

// Pass 1: per-edge energy, full lane efficiency, computed exactly once.
// E[e] = 0 for d > cutoff (scatter then skips the LDS add).
__global__ __launch_bounds__(256) void pc_compute_E(
    const float* __restrict__ q,
    const float* __restrict__ dip,
    const float* __restrict__ dist,
    const int*   __restrict__ idx_i,
    const int*   __restrict__ idx_j,
    float*       __restrict__ E,
    int n_edges, int n4)
{
    int t = blockIdx.x * 256 + threadIdx.x;

    if (t < n4) {
        float4 d4 = ((const float4*)dist)[t];
        int4   i4 = ((const int4*)idx_i)[t];
        int4   j4 = ((const int4*)idx_j)[t];
        float4 e4;
        #pragma unroll
        for (int k = 0; k < 4; ++k) {
            float d = (k == 0) ? d4.x : (k == 1) ? d4.y : (k == 2) ? d4.z : d4.w;
            int   i = (k == 0) ? i4.x : (k == 1) ? i4.y : (k == 2) ? i4.z : i4.w;
            int   j = (k == 0) ? j4.x : (k == 1) ? j4.y : (k == 2) ? j4.z : j4.w;
            float e = (d <= CUTOFF_C)
                        ? edge_energy(d, q[i], q[j], dip[i], dip[j]) : 0.0f;
            if (k == 0) e4.x = e; else if (k == 1) e4.y = e;
            else if (k == 2) e4.z = e; else e4.w = e;
        }
        ((float4*)E)[t] = e4;
    }

    // tail (n_edges % 4); empty for 6.4M edges but kept for generality
    int total = gridDim.x * 256;
    for (int e = (n4 << 2) + t; e < n_edges; e += total) {
        float d = dist[e];
        E[e] = (d <= CUTOFF_C)
                 ? edge_energy(d, q[idx_i[e]], q[idx_j[e]],
                               dip[idx_i[e]], dip[idx_j[e]]) : 0.0f;
    }
}

// Pass 2: block (s, c) streams slice s of (idx_i, E), accumulates chunk c
// into LDS, flushes with plain coalesced stores. Cheap inner loop: load,
// range-check, masked ds_add — no transcendentals in the replicated path.
__global__ __launch_bounds__(BLOCK_SC) void pc_scatter(
    const int*   __restrict__ idx_i,
    const float* __restrict__ E,
    float*       __restrict__ partial,   // [S][n_atoms]
    int n_edges, int n4, int S, int gps, int n_atoms, int swz)
{
    __shared__ float acc[CHUNK];

    int s, c;
    if (swz) {
        // Same-slice blocks share blockIdx%8 -> (heuristically) same XCD,
        // so the 7 re-reads of a slice can hit that XCD's L2.
        int x = blockIdx.x & 7;
        int r = blockIdx.x >> 3;       // 0..62 (S=72: 9 slices * 7 chunks)
        s = x * 9 + r / NCHUNK;
        c = r % NCHUNK;
    } else {
        c = blockIdx.x % NCHUNK;
        s = blockIdx.x / NCHUNK;
    }
    const int base = c * CHUNK;

    for (int i = threadIdx.x; i < CHUNK; i += BLOCK_SC) acc[i] = 0.0f;
    __syncthreads();

    const int g0 = s * gps;
    const int g1 = min(g0 + gps, n4);
    const int4*   idxi4 = (const int4*)idx_i;
    const float4* E4p   = (const float4*)E;

    for (int g = g0 + (int)threadIdx.x; g < g1; g += BLOCK_SC) {
        int4   i4 = idxi4[g];
        float4 e4 = E4p[g];
        #pragma unroll
        for (int k = 0; k < 4; ++k) {
            int   i = (k == 0) ? i4.x : (k == 1) ? i4.y : (k == 2) ? i4.z : i4.w;
            float e = (k == 0) ? e4.x : (k == 1) ? e4.y : (k == 2) ? e4.z : e4.w;
            unsigned local = (unsigned)(i - base);
            if (local < (unsigned)CHUNK && e != 0.0f)
                atomicAdd(&acc[local], e);
        }
    }

    if (s == S - 1) {  // scalar tail
        for (int e = (n4 << 2) + (int)threadIdx.x; e < n_edges; e += BLOCK_SC) {
            unsigned local = (unsigned)(idx_i[e] - base);
            float ev = E[e];
            if (local < (unsigned)CHUNK && ev != 0.0f)
                atomicAdd(&acc[local], ev);
        }
    }

    __syncthreads();
    int lim = min(CHUNK, n_atoms - base);
    float* row = partial + (size_t)s * n_atoms + base;
    for (int i = threadIdx.x; i < lim; i += BLOCK_SC) row[i] = acc[i];
}

// Pass 3: out[a] = sum_s partial[s][a]. 4 waves/block each sum S/4 slices
// for 64 atoms; LDS combine. 1563 blocks -> plenty of TLP.
__global__ __launch_bounds__(256) void pc_reduce(
    const float* __restrict__ partial,
    float*       __restrict__ out,
    int n_atoms, int S)
{
    __shared__ float sh[256];
    int a0   = blockIdx.x * 64;
    int lane = threadIdx.x & 63;
    int w    = threadIdx.x >> 6;
    int a    = a0 + lane;

    float v0 = 0.0f, v1 = 0.0f;
    if (a < n_atoms) {
        int per = S >> 2;                 // S % 4 == 0
        const float* p = partial + a;
        int s = w * per, send = s + per;
        for (; s + 2 <= send; s += 2) {
            v0 += p[(size_t)(s + 0) * n_atoms];
            v1 += p[(size_t)(s + 1) * n_atoms];
        }
        for (; s < send; ++s) v0 += p[(size_t)s * n_atoms];
    }
    sh[threadIdx.x] = v0 + v1;
    __syncthreads();
    if (w == 0 && a < n_atoms)
        out[a] = (sh[lane] + sh[64 + lane]) + (sh[128 + lane] + sh[192 + lane]);
}

// Fallback: round-1 global-atomic kernel (only if ws is unexpectedly tiny).
__global__ __launch_bounds__(256) void pc_dipole_edges_atomic(
    const float* __restrict__ q,
    const float* __restrict__ dip,
    const float* __restrict__ dist,
    const int*   __restrict__ idx_i,
    const int*   __restrict__ idx_j,
    float*       __restrict__ out,
    int n_edges)
{
    int t = blockIdx.x * blockDim.x + threadIdx.x;
    const int stride = gridDim.x * blockDim.x;
    for (int e = t; e < n_edges; e += stride) {
        float d = dist[e];
        if (d > CUTOFF_C) continue;
        int i = idx_i[e], j = idx_j[e];
        atomicAdd(&out[i], edge_energy(d, q[i], q[j], dip[i], dip[j]));
    }
}

extern "C" void kernel_launch(void* const* d_in, const int* in_sizes, int n_in,
                              void* d_out, int out_size, void* d_ws, size_t ws_size,
                              hipStream_t stream) {
    const float* q     = (const float*)d_in[0];
    const float* dip   = (const float*)d_in[1];
    const float* dist  = (const float*)d_in[2];
    const int*   idx_i = (const int*)d_in[3];
    const int*   idx_j = (const int*)d_in[4];
    float*       out   = (float*)d_out;

    int n_edges = in_sizes[2];
    int n_atoms = out_size;
    int n4      = n_edges >> 2;

    // Workspace layout: [E: n_edges floats][partial: S * n_atoms floats]
    size_t e_bytes = ((size_t)n_edges * sizeof(float) + 255) & ~(size_t)255;
    size_t avail   = (ws_size > e_bytes) ? ws_size - e_bytes : 0;
    int S = (int)((avail / ((size_t)n_atoms * sizeof(float))));
    if (S > S_FULL) S = S_FULL;
    S &= ~3;  // reduce kernel needs S % 4 == 0

    if (S >= 8 && n_atoms <= NCHUNK * CHUNK) {
        float* E       = (float*)d_ws;
        float* partial = (float*)((char*)d_ws + e_bytes);
        int    swz     = (S == S_FULL) ? 1 : 0;
        int    gps     = (n4 + S - 1) / S;

        int grid1 = (n4 + 255) / 256;
        if (grid1 < 1) grid1 = 1;
        pc_compute_E<<<grid1, 256, 0, stream>>>(q, dip, dist, idx_i, idx_j,
                                                E, n_edges, n4);
        pc_scatter<<<S * NCHUNK, BLOCK_SC, 0, stream>>>(
            idx_i, E, partial, n_edges, n4, S, gps, n_atoms, swz);
        pc_reduce<<<(n_atoms + 63) / 64, 256, 0, stream>>>(partial, out,
                                                           n_atoms, S);
    } else {
        hipMemsetAsync(out, 0, (size_t)n_atoms * sizeof(float), stream);
        int grid = (n_edges + 255) / 256;
        pc_dipole_edges_atomic<<<grid, 256, 0, stream>>>(
            q, dip, dist, idx_i, idx_j, out, n_edges);
    }
}

// Round 4
// 200.924 us; speedup vs baseline: 1.9527x; 1.1864x over previous
//
#include <hip/hip_runtime.h>
#include <hip/hip_bf16.h>

// Problem constants (match reference)
#define CUTOFF_C    12.0f
#define CUTOFF_SR_C 2.0f
#define CUTOFF_SQ_C 144.0f
#define KEHALF_C    7.199822675975274f

#define CHUNK    16000     // 64000 B LDS accumulator (<= 64 KiB static limit)
#define NCHUNK   7         // ceil(100000 / 16000)
#define BLOCK_SC 512       // scatter block: 8 waves; 2 blocks/CU by LDS
#define S_FULL   72        // 72*7 = 504 blocks ~= 2/CU; 72 = 8 XCDs * 9

__device__ __forceinline__ float edge_energy(float d, float qi, float qj,
                                             float di, float dj) {
    float inv_d   = __frcp_rn(d);
    float dsh     = __fsqrt_rn(fmaf(d, d, 1.0f));
    float inv_dsh = __frcp_rn(dsh);

    // poly6 switch on [0, CUTOFF_SR): 1 - 10x^3 + 15x^4 - 6x^5
    float x  = d * (1.0f / CUTOFF_SR_C);
    float x3 = x * x * x;
    float sw = fmaf(x3, fmaf(x, fmaf(x, -6.0f, 15.0f), -10.0f), 1.0f);
    float sw_off = (d < CUTOFF_SR_C) ? sw : 0.0f;

    float Eoq = inv_d   + fmaf(d,   (1.0f / CUTOFF_SQ_C), -(2.0f / CUTOFF_C));
    float Esq = inv_dsh + fmaf(dsh, (1.0f / CUTOFF_SQ_C), -(2.0f / CUTOFF_C));
    float Eq  = (KEHALF_C * qi * qj) * fmaf(sw_off, Esq - Eoq, Eoq);

    float Eod = inv_d * inv_d * inv_d;
    float Esd = inv_dsh * inv_dsh * inv_dsh;
    float Ed  = (KEHALF_C * di * dj) * fmaf(sw_off, Esd - Eod, Eod);

    return Eq + Ed;
}

// Pass 0: pack {q, dip} into float2 so each edge endpoint is ONE 8B gather
// instead of two 4B gathers (halves gather instructions and L2->L1 lines).
__global__ __launch_bounds__(256) void pc_pack_qd(
    const float* __restrict__ q,
    const float* __restrict__ dip,
    float2*      __restrict__ qd,
    int n_atoms)
{
    int a = blockIdx.x * 256 + threadIdx.x;
    if (a < n_atoms) qd[a] = make_float2(q[a], dip[a]);
}

// Pass 1: per-edge energy, full lane efficiency, computed exactly once.
// E[e] = 0 for d > cutoff (scatter then skips the LDS add).
__global__ __launch_bounds__(256) void pc_compute_E(
    const float2* __restrict__ qd,
    const float*  __restrict__ dist,
    const int*    __restrict__ idx_i,
    const int*    __restrict__ idx_j,
    float*        __restrict__ E,
    int n_edges, int n4)
{
    int t = blockIdx.x * 256 + threadIdx.x;

    if (t < n4) {
        float4 d4 = ((const float4*)dist)[t];
        int4   i4 = ((const int4*)idx_i)[t];
        int4   j4 = ((const int4*)idx_j)[t];
        float4 e4;
        #pragma unroll
        for (int k = 0; k < 4; ++k) {
            float d = (k == 0) ? d4.x : (k == 1) ? d4.y : (k == 2) ? d4.z : d4.w;
            int   i = (k == 0) ? i4.x : (k == 1) ? i4.y : (k == 2) ? i4.z : i4.w;
            int   j = (k == 0) ? j4.x : (k == 1) ? j4.y : (k == 2) ? j4.z : j4.w;
            float2 qdi = qd[i];
            float2 qdj = qd[j];
            float e = (d <= CUTOFF_C)
                        ? edge_energy(d, qdi.x, qdj.x, qdi.y, qdj.y) : 0.0f;
            if (k == 0) e4.x = e; else if (k == 1) e4.y = e;
            else if (k == 2) e4.z = e; else e4.w = e;
        }
        ((float4*)E)[t] = e4;
    }

    // tail (n_edges % 4); empty for 6.4M edges but kept for generality
    int total = gridDim.x * 256;
    for (int e = (n4 << 2) + t; e < n_edges; e += total) {
        float d = dist[e];
        float2 qdi = qd[idx_i[e]];
        float2 qdj = qd[idx_j[e]];
        E[e] = (d <= CUTOFF_C)
                 ? edge_energy(d, qdi.x, qdj.x, qdi.y, qdj.y) : 0.0f;
    }
}

// Pass 2: block (s, c) streams slice s of (idx_i, E), accumulates chunk c
// into LDS, flushes with plain coalesced stores. Cheap inner loop: load,
// range-check, masked ds_add — no transcendentals in the replicated path.
__global__ __launch_bounds__(BLOCK_SC) void pc_scatter(
    const int*   __restrict__ idx_i,
    const float* __restrict__ E,
    float*       __restrict__ partial,   // [S][n_atoms]
    int n_edges, int n4, int S, int gps, int n_atoms, int swz)
{
    __shared__ float acc[CHUNK];

    int s, c;
    if (swz) {
        // Same-slice blocks share blockIdx%8 -> (heuristically) same XCD,
        // so the 7 re-reads of a slice can hit that XCD's L2.
        int x = blockIdx.x & 7;
        int r = blockIdx.x >> 3;       // 0..62 (S=72: 9 slices * 7 chunks)
        s = x * 9 + r / NCHUNK;
        c = r % NCHUNK;
    } else {
        c = blockIdx.x % NCHUNK;
        s = blockIdx.x / NCHUNK;
    }
    const int base = c * CHUNK;

    for (int i = threadIdx.x; i < CHUNK; i += BLOCK_SC) acc[i] = 0.0f;
    __syncthreads();

    const int g0 = s * gps;
    const int g1 = min(g0 + gps, n4);
    const int4*   idxi4 = (const int4*)idx_i;
    const float4* E4p   = (const float4*)E;

    for (int g = g0 + (int)threadIdx.x; g < g1; g += BLOCK_SC) {
        int4   i4 = idxi4[g];
        float4 e4 = E4p[g];
        #pragma unroll
        for (int k = 0; k < 4; ++k) {
            int   i = (k == 0) ? i4.x : (k == 1) ? i4.y : (k == 2) ? i4.z : i4.w;
            float e = (k == 0) ? e4.x : (k == 1) ? e4.y : (k == 2) ? e4.z : e4.w;
            unsigned local = (unsigned)(i - base);
            if (local < (unsigned)CHUNK && e != 0.0f)
                atomicAdd(&acc[local], e);
        }
    }

    if (s == S - 1) {  // scalar tail
        for (int e = (n4 << 2) + (int)threadIdx.x; e < n_edges; e += BLOCK_SC) {
            unsigned local = (unsigned)(idx_i[e] - base);
            float ev = E[e];
            if (local < (unsigned)CHUNK && ev != 0.0f)
                atomicAdd(&acc[local], ev);
        }
    }

    __syncthreads();
    int lim = min(CHUNK, n_atoms - base);
    float* row = partial + (size_t)s * n_atoms + base;
    for (int i = threadIdx.x; i < lim; i += BLOCK_SC) row[i] = acc[i];
}

// Pass 3: out[a] = sum_s partial[s][a]. 4 waves/block each sum S/4 slices
// for 64 atoms; LDS combine. 1563 blocks -> plenty of TLP.
__global__ __launch_bounds__(256) void pc_reduce(
    const float* __restrict__ partial,
    float*       __restrict__ out,
    int n_atoms, int S)
{
    __shared__ float sh[256];
    int a0   = blockIdx.x * 64;
    int lane = threadIdx.x & 63;
    int w    = threadIdx.x >> 6;
    int a    = a0 + lane;

    float v0 = 0.0f, v1 = 0.0f;
    if (a < n_atoms) {
        int per = S >> 2;                 // S % 4 == 0
        const float* p = partial + a;
        int s = w * per, send = s + per;
        for (; s + 2 <= send; s += 2) {
            v0 += p[(size_t)(s + 0) * n_atoms];
            v1 += p[(size_t)(s + 1) * n_atoms];
        }
        for (; s < send; ++s) v0 += p[(size_t)s * n_atoms];
    }
    sh[threadIdx.x] = v0 + v1;
    __syncthreads();
    if (w == 0 && a < n_atoms)
        out[a] = (sh[lane] + sh[64 + lane]) + (sh[128 + lane] + sh[192 + lane]);
}

// Fallback: global-atomic kernel (only if ws is unexpectedly tiny).
__global__ __launch_bounds__(256) void pc_dipole_edges_atomic(
    const float* __restrict__ q,
    const float* __restrict__ dip,
    const float* __restrict__ dist,
    const int*   __restrict__ idx_i,
    const int*   __restrict__ idx_j,
    float*       __restrict__ out,
    int n_edges)
{
    int t = blockIdx.x * blockDim.x + threadIdx.x;
    const int stride = gridDim.x * blockDim.x;
    for (int e = t; e < n_edges; e += stride) {
        float d = dist[e];
        if (d > CUTOFF_C) continue;
        int i = idx_i[e], j = idx_j[e];
        atomicAdd(&out[i], edge_energy(d, q[i], q[j], dip[i], dip[j]));
    }
}

extern "C" void kernel_launch(void* const* d_in, const int* in_sizes, int n_in,
                              void* d_out, int out_size, void* d_ws, size_t ws_size,
                              hipStream_t stream) {
    const float* q     = (const float*)d_in[0];
    const float* dip   = (const float*)d_in[1];
    const float* dist  = (const float*)d_in[2];
    const int*   idx_i = (const int*)d_in[3];
    const int*   idx_j = (const int*)d_in[4];
    float*       out   = (float*)d_out;

    int n_edges = in_sizes[2];
    int n_atoms = out_size;
    int n4      = n_edges >> 2;

    // Workspace layout: [qd: n_atoms float2][E: n_edges f32][partial: S*n_atoms]
    size_t qd_bytes = ((size_t)n_atoms * sizeof(float2) + 255) & ~(size_t)255;
    size_t e_bytes  = ((size_t)n_edges * sizeof(float) + 255) & ~(size_t)255;
    size_t head     = qd_bytes + e_bytes;
    size_t avail    = (ws_size > head) ? ws_size - head : 0;
    int S = (int)(avail / ((size_t)n_atoms * sizeof(float)));
    if (S > S_FULL) S = S_FULL;
    S &= ~3;  // reduce kernel needs S % 4 == 0

    if (S >= 8 && n_atoms <= NCHUNK * CHUNK) {
        float2* qd      = (float2*)d_ws;
        float*  E       = (float*)((char*)d_ws + qd_bytes);
        float*  partial = (float*)((char*)d_ws + head);
        int     swz     = (S == S_FULL) ? 1 : 0;
        int     gps     = (n4 + S - 1) / S;

        pc_pack_qd<<<(n_atoms + 255) / 256, 256, 0, stream>>>(q, dip, qd,
                                                              n_atoms);
        int grid1 = (n4 + 255) / 256;
        if (grid1 < 1) grid1 = 1;
        pc_compute_E<<<grid1, 256, 0, stream>>>(qd, dist, idx_i, idx_j,
                                                E, n_edges, n4);
        pc_scatter<<<S * NCHUNK, BLOCK_SC, 0, stream>>>(
            idx_i, E, partial, n_edges, n4, S, gps, n_atoms, swz);
        pc_reduce<<<(n_atoms + 63) / 64, 256, 0, stream>>>(partial, out,
                                                           n_atoms, S);
    } else {
        hipMemsetAsync(out, 0, (size_t)n_atoms * sizeof(float), stream);
        int grid = (n_edges + 255) / 256;
        pc_dipole_edges_atomic<<<grid, 256, 0, stream>>>(
            q, dip, dist, idx_i, idx_j, out, n_edges);
    }
}